// Round 3
// baseline (659.844 us; speedup 1.0000x reference)
//
#include <hip/hip_runtime.h>

#define VOCAB   50000
#define EMBED   128
#define NTOT    200000
#define BATCH   1024
#define NTILE   128
#define NBLKS   1563          // ceil(NTOT/NTILE); last tile has 64 valid cols
#define MCHUNK  128
#define NCHUNKS 8             // BATCH / MCHUNK
#define NSEG    (NBLKS * 2)   // partial-sum segments (2 waves share rows)

typedef __attribute__((ext_vector_type(8))) __bf16 bf16x8;
typedef __attribute__((ext_vector_type(4))) float f32x4;

__device__ __forceinline__ unsigned int f2bf(float f) {
  unsigned int u = __float_as_uint(f);
  u += 0x7FFFu + ((u >> 16) & 1u);   // RNE
  return u >> 16;
}

// h[b][e] = bf16(relu(W1[e][idx[b]])), linear row-major [1024][128]
__global__ void build_h_kernel(const int* __restrict__ idx,
                               const float* __restrict__ W1,
                               unsigned short* __restrict__ h) {
  int g = blockIdx.x * 256 + threadIdx.x;   // 131072 = 1024*128
  int b = g >> 7, e = g & 127;
  float v = W1[(size_t)e * VOCAB + idx[b]];
  h[g] = (unsigned short)f2bf(fmaxf(v, 0.f));
}

// One block owns 128 output cols (n0..n0+127) for the whole batch.
// W2 tile in LDS (32KB, XOR-swizzled, staged once -> ONE barrier total).
// A-fragments load straight from global h (L2-resident, 256KB) each chunk.
// PASS==1: partial[seg][m] = per-row sum of exp(logits), seg = nb*2+wn.
// PASS==2: out[m][n] = lse[m] - logit[m][n], nontemporal 4B stores.
template <int PASS>
__global__ __launch_bounds__(256, 3)
void gemm_pass(const float* __restrict__ W2,
               const unsigned short* __restrict__ h,
               float* __restrict__ partial,
               const float* __restrict__ lse,
               float* __restrict__ out) {
  __shared__ __align__(16) char wt[NTILE * 256];  // bf16 W2 tile, swizzled
  __shared__ float lse_s[BATCH];                  // pass2 lse cache (4KB)

  const int t    = threadIdx.x;
  const int nb   = blockIdx.x;
  const int n0   = nb * NTILE;
  const int lane = t & 63;
  const int wid  = t >> 6;
  const int wm   = wid >> 1, wn = wid & 1;   // 2x2 waves over 128x128 tile
  const int kg   = lane >> 4, rl = lane & 15;
  const bool edge = (n0 + NTILE > NTOT);

  // ---- stage W2 tile once: 128 rows x 128 f32 -> bf16, swizzled ----
  #pragma unroll
  for (int i = 0; i < 16; ++i) {
    int u = t + 256 * i;                     // 4096 float4 units
    int r = u >> 5, p8 = u & 31;
    int srow = n0 + r; if (srow >= NTOT) srow = NTOT - 1;
    const float4 v = *(const float4*)(W2 + (size_t)srow * EMBED + p8 * 4);
    uint2 d;
    d.x = f2bf(v.x) | (f2bf(v.y) << 16);
    d.y = f2bf(v.z) | (f2bf(v.w) << 16);
    *(uint2*)(wt + r * 256 + ((p8 * 8) ^ ((r & 7) << 4))) = d;
  }
  if (PASS == 2) {
    #pragma unroll
    for (int i = 0; i < 4; ++i) lse_s[t + 256 * i] = lse[t + 256 * i];
  }
  __syncthreads();   // the ONLY barrier in this kernel

  const char* hb = (const char*)h;

  for (int c = 0; c < NCHUNKS; ++c) {
    const int m0 = c * MCHUNK;

    f32x4 acc[4][4];
    #pragma unroll
    for (int a = 0; a < 4; ++a)
      #pragma unroll
      for (int b = 0; b < 4; ++b)
        acc[a][b] = (f32x4){0.f, 0.f, 0.f, 0.f};

    // per-lane A row base: row = m0 + wm*64 + fm*16 + rl, fm stride = 4096B
    const char* abase = hb + (size_t)(m0 + wm * 64 + rl) * 256 + kg * 16;

    #pragma unroll
    for (int kk = 0; kk < 4; ++kk) {
      bf16x8 af[4], bf_[4];
      #pragma unroll
      for (int fm = 0; fm < 4; ++fm)
        af[fm] = *(const bf16x8*)(abase + fm * 4096 + kk * 64);
      #pragma unroll
      for (int fn = 0; fn < 4; ++fn) {
        int r = wn * 64 + fn * 16 + rl;
        bf_[fn] = *(const bf16x8*)(wt + r * 256 + ((kk * 64 + kg * 16) ^ ((r & 7) << 4)));
      }
      #pragma unroll
      for (int fm = 0; fm < 4; ++fm)
        #pragma unroll
        for (int fn = 0; fn < 4; ++fn)
          acc[fm][fn] = __builtin_amdgcn_mfma_f32_16x16x32_bf16(
              af[fm], bf_[fn], acc[fm][fn], 0, 0, 0);
    }

    if (PASS == 1) {
      float msk[4];
      #pragma unroll
      for (int fn = 0; fn < 4; ++fn)
        msk[fn] = (n0 + wn * 64 + fn * 16 + rl < NTOT) ? 1.0f : 0.0f;
      #pragma unroll
      for (int fm = 0; fm < 4; ++fm)
        #pragma unroll
        for (int j = 0; j < 4; ++j) {
          float s;
          if (edge)
            s = msk[0] * __expf(acc[fm][0][j]) + msk[1] * __expf(acc[fm][1][j])
              + msk[2] * __expf(acc[fm][2][j]) + msk[3] * __expf(acc[fm][3][j]);
          else
            s = __expf(acc[fm][0][j]) + __expf(acc[fm][1][j])
              + __expf(acc[fm][2][j]) + __expf(acc[fm][3][j]);
          s += __shfl_xor(s, 1);
          s += __shfl_xor(s, 2);
          s += __shfl_xor(s, 4);
          s += __shfl_xor(s, 8);
          if (rl == 0)
            partial[((size_t)nb * 2 + wn) * BATCH +
                    m0 + wm * 64 + fm * 16 + kg * 4 + j] = s;
        }
    } else {
      #pragma unroll
      for (int fm = 0; fm < 4; ++fm)
        #pragma unroll
        for (int j = 0; j < 4; ++j) {
          int row = m0 + wm * 64 + fm * 16 + kg * 4 + j;
          float l = lse_s[row];
          float* op = out + (size_t)row * NTOT + n0 + wn * 64 + rl;
          #pragma unroll
          for (int fn = 0; fn < 4; ++fn) {
            if (!edge || (n0 + wn * 64 + fn * 16 + rl) < NTOT)
              __builtin_nontemporal_store(l - acc[fm][fn][j], op + fn * 16);
          }
        }
    }
  }
}

// lse[m] = log( sum_seg partial[seg][m] ); coalesced (lanes -> consecutive m)
__global__ void reduce_lse_kernel(const float* __restrict__ partial,
                                  float* __restrict__ lse) {
  __shared__ float sb[4][64];
  const int ml = threadIdx.x & 63;
  const int ks = threadIdx.x >> 6;
  const int m  = blockIdx.x * 64 + ml;
  float s = 0.f;
  for (int seg = ks; seg < NSEG; seg += 4)
    s += partial[(size_t)seg * BATCH + m];
  sb[ks][ml] = s;
  __syncthreads();
  if (threadIdx.x < 64) {
    float tot = sb[0][threadIdx.x] + sb[1][threadIdx.x] +
                sb[2][threadIdx.x] + sb[3][threadIdx.x];
    lse[blockIdx.x * 64 + threadIdx.x] = logf(tot);
  }
}

extern "C" void kernel_launch(void* const* d_in, const int* in_sizes, int n_in,
                              void* d_out, int out_size, void* d_ws, size_t ws_size,
                              hipStream_t stream) {
  const int*   idx = (const int*)d_in[0];
  const float* W1  = (const float*)d_in[1];
  const float* W2  = (const float*)d_in[2];
  float* out = (float*)d_out;

  // ws: h linear bf16 (256KB) | lse (4KB)
  unsigned short* h   = (unsigned short*)d_ws;
  float*          lse = (float*)((char*)d_ws + 262144);

  // partials live at the head of d_out (12.8MB), consumed by reduce_lse
  // before pass 2 overwrites every output element.
  float* partial = out;

  build_h_kernel<<<512, 256, 0, stream>>>(idx, W1, h);
  gemm_pass<1><<<NBLKS, 256, 0, stream>>>(W2, h, partial, nullptr, nullptr);
  reduce_lse_kernel<<<BATCH / 64, 256, 0, stream>>>(partial, lse);
  gemm_pass<2><<<NBLKS, 256, 0, stream>>>(W2, h, nullptr, lse, out);
}